// Round 6
// baseline (367.710 us; speedup 1.0000x reference)
//
#include <hip/hip_runtime.h>
#include <hip/hip_bf16.h>
#include <stdint.h>

#define N_NODES  50000
#define N_GRAPHS 256
#define DIM      128
#define N_EDGES  800000
#define K2       256            // fused K = [agg | h]
#define N_STRIPS (N_NODES / 16) // 3125, exact
#define PAD_CAP  64             // max degree slack (mean 16; fixed edge list, no overflow)

typedef __attribute__((ext_vector_type(8))) short  short8;
typedef __attribute__((ext_vector_type(4))) float  floatx4;
typedef __attribute__((ext_vector_type(4))) int    intx4;

__device__ __forceinline__ ushort f2bf(float f) {
    union { float f; uint32_t u; } c; c.f = f;
    uint32_t u = c.u;
    return (ushort)((u + 0x7fffu + ((u >> 16) & 1u)) >> 16);  // RNE
}

// ---------- fused prep: convert_x | prep_w | gbounds | cnt-zero | out-zero ----------
#define MB_CONV 6250
#define MB_PREPW (MB_CONV + 384)
#define MB_GB   (MB_PREPW + 196)
#define MB_CNT  (MB_GB + 196)
#define MB_OUT  (MB_CNT + 256)
__global__ __launch_bounds__(256) void k_misc(const float* __restrict__ x, ushort* __restrict__ xb,
                                              const float* __restrict__ Wl0, const float* __restrict__ Wr0,
                                              const float* __restrict__ Wl1, const float* __restrict__ Wr1,
                                              const float* __restrict__ Wl2, const float* __restrict__ Wr2,
                                              ushort* __restrict__ Wt,
                                              const int* __restrict__ batch,
                                              int* __restrict__ gstart, int* __restrict__ gend,
                                              int* __restrict__ cnt, float* __restrict__ out) {
    int b = blockIdx.x, t = threadIdx.x;
    if (b < MB_CONV) {                       // fp32 x -> bf16 (float4 granularity)
        int i = b * 256 + t;                 // i < 1.6M exactly
        float4 v = ((const float4*)x)[i];
        uint32_t lo = (uint32_t)f2bf(v.x) | ((uint32_t)f2bf(v.y) << 16);
        uint32_t hi = (uint32_t)f2bf(v.z) | ((uint32_t)f2bf(v.w) << 16);
        ((uint2*)xb)[i] = make_uint2(lo, hi);
    } else if (b < MB_PREPW) {               // Wt[l][n][k] = bf16(k<128 ? Wl[k][n] : Wr[k-128][n])
        int i = (b - MB_CONV) * 256 + t;     // i < 98304 exactly
        int layer = i / (DIM * K2);
        int j = i % (DIM * K2);
        int n = j / K2, k = j % K2;
        const float* Wl = (layer == 0) ? Wl0 : (layer == 1) ? Wl1 : Wl2;
        const float* Wr = (layer == 0) ? Wr0 : (layer == 1) ? Wr1 : Wr2;
        float v = (k < DIM) ? Wl[k * DIM + n] : Wr[(k - DIM) * DIM + n];
        Wt[i] = f2bf(v);
    } else if (b < MB_GB) {                  // per-graph node ranges from sorted batch
        int i = (b - MB_PREPW) * 256 + t;
        if (i < N_NODES) {
            int g = batch[i];
            if (i == 0) gstart[g] = 0;
            int gn = (i + 1 < N_NODES) ? batch[i + 1] : -1;
            if (gn != g) {
                gend[g] = i + 1;
                if (gn >= 0) gstart[gn] = i + 1;
            }
        }
    } else if (b < MB_CNT) {                 // zero degree counters (pre-build)
        int i = (b - MB_GB) * 256 + t;
        if (i < N_NODES) cnt[i] = 0;
    } else {                                 // zero output (pre-readout atomics)
        int i = (b - MB_CNT) * 256 + t;
        if (i < N_GRAPHS * 2 * DIM) out[i] = 0.f;
    }
}

// ---------- direct adjacency build: one kernel, global atomics ----------
// Insertion order is nondeterministic; k_layer<0> sorts each list before any use, so
// every consumer sees a canonical (ascending) list. Scatter write is nontemporal to
// avoid read-for-ownership traffic on the random 4B writes.
__global__ __launch_bounds__(256) void k_build_direct(const int* __restrict__ src,
                                                      const int* __restrict__ dst,
                                                      int* __restrict__ cnt,
                                                      int* __restrict__ padded) {
    int i = blockIdx.x * 256 + threadIdx.x;
    if (i < N_EDGES) {
        int d = dst[i], s = src[i];
        int p = atomicAdd(&cnt[d], 1);
        if (p < PAD_CAP) __builtin_nontemporal_store(s, &padded[(size_t)d * PAD_CAP + p]);
    }
}

// ---------- fused SAGE layer: barrier-free, one wave = one 16-row strip ----------
// Each wave owns a full strip: stages its 16 neighbor lists into a private 4 KB LDS
// region, gathers with the register double-buffer (16 loads in flight), writes each
// node's bf16 agg row OVER that node's dead idx row (idx row q is last read when node
// q's final chunk issues, strictly before its finalize) — so LDS is 17.9 KB/block and
// 8+ blocks/CU co-reside with NO __syncthreads anywhere (no 4-wave imbalance tax).
// MODE 0: in-wave bitonic sort of each list + canonical writeback for layers 1-2.
// MODE 1: plain (bf16 out). MODE 2: in-register segmented mean/max readout (no h3).
template <int MODE>
__global__ __launch_bounds__(256) void k_layer(const ushort* __restrict__ h_in,
                                               int* __restrict__ padded,
                                               const int* __restrict__ cnt,
                                               const ushort* __restrict__ Wt,
                                               const float* __restrict__ bias,
                                               ushort* __restrict__ out_bf,
                                               const int* __restrict__ batch,
                                               float* __restrict__ gout) {
    __shared__ int sIA[4][16 * 64];                // 16 KB: idx lists -> agg rows (aliased)
    __shared__ int sCnt[4][16];
    __shared__ int sChl[4][65];                    // chunk list: q | (e0<<8), <=64 chunks
    __shared__ int sGb[4][16];

    int t     = threadIdx.x;
    int wid   = t >> 6;
    int lane  = t & 63;
    int strip = blockIdx.x * 4 + wid;
    if (strip >= N_STRIPS) return;                 // no barriers -> early exit is safe
    int r0    = strip * 16;
    int* sIdx = sIA[wid];
    const uint32_t* hw = (const uint32_t*)h_in;    // 64 dwords per row

    // ---- stage neighbor lists + degrees (coalesced; wave-local LDS, in-order DS pipe) ----
    const intx4* gsrc = (const intx4*)(padded + (size_t)r0 * PAD_CAP);
    #pragma unroll
    for (int it = 0; it < 4; ++it)
        ((intx4*)sIdx)[it * 64 + lane] = __builtin_nontemporal_load(gsrc + it * 64 + lane);
    if (lane < 16) sCnt[wid][lane] = cnt[r0 + lane];
    if (MODE == 2 && lane >= 16 && lane < 32) sGb[wid][lane - 16] = batch[r0 + lane - 16];

    // ---- MODE 0: canonicalize lists in-wave (16 sequential 64-lane bitonics) ----
    if (MODE == 0) {
        #pragma unroll 1
        for (int q = 0; q < 16; ++q) {
            int m = min(sCnt[wid][q], PAD_CAP);
            int* lst = sIdx + q * 64;
            int v = (lane < m) ? lst[lane] : 0x7fffffff;   // pads sort to the end
            #pragma unroll
            for (int k = 2; k <= 64; k <<= 1) {
                #pragma unroll
                for (int j = k >> 1; j > 0; j >>= 1) {
                    int other  = __shfl_xor(v, j, 64);
                    bool down  = (lane & k) != 0;
                    bool lower = (lane & j) == 0;
                    v = (lower ^ down) ? min(v, other) : max(v, other);
                }
            }
            if (lane < m) {
                lst[lane] = v;                             // canonical, wave-local
                __builtin_nontemporal_store(v,             // for layers 1-2
                    &padded[(size_t)(r0 + q) * PAD_CAP + lane]);
            }
        }
    }

    // ---- flattened chunk list (lane 0 writes; same-wave LDS read-back is in-order) ----
    if (lane == 0) {
        int n = 0;
        #pragma unroll 1
        for (int q = 0; q < 16; ++q) {
            int m = min(sCnt[wid][q], PAD_CAP);
            for (int e0 = 0; e0 < m; e0 += 16)
                sChl[wid][n++] = q | (e0 << 8);
        }
        sChl[wid][64] = n;
    }
    // zero agg rows for isolated nodes (no chunks emitted for them)
    #pragma unroll 1
    for (int q = 0; q < 16; ++q)
        if (sCnt[wid][q] == 0) ((uint32_t*)(sIdx + q * 64))[lane] = 0u;
    int nch = sChl[wid][64];

    float ax[4] = {0.f, 0.f, 0.f, 0.f};
    float ay[4] = {0.f, 0.f, 0.f, 0.f};
    uint32_t va[16], vb[16];                       // double-buffered gather rows

    auto issue = [&](int ci, uint32_t (&v)[16]) {
        int ch = sChl[wid][ci];
        int q  = ch & 255, e0 = ch >> 8;
        int m  = min(sCnt[wid][q], PAD_CAP);
        const int* lst = sIdx + q * 64;
        #pragma unroll
        for (int k = 0; k < 16; ++k) {
            int ek = e0 + k;
            int id = lst[ek < m ? ek : m - 1];     // LDS broadcast; m>=1 here
            v[k] = hw[(size_t)id * 64 + lane];     // 16 row loads in flight
        }
    };
    auto consume = [&](int ci, uint32_t (&v)[16], bool isLast) {
        int ch  = sChl[wid][ci];
        int q   = ch & 255, e0 = ch >> 8;
        int deg = sCnt[wid][q];
        int m   = min(deg, PAD_CAP);
        #pragma unroll
        for (int k = 0; k < 16; ++k) {
            uint32_t w = (e0 + k < m) ? v[k] : 0u; // predicated tail (bf16 +0.0)
            ax[k & 3] += __uint_as_float(w << 16);
            ay[k & 3] += __uint_as_float(w & 0xffff0000u);
        }
        bool lastOfNode = isLast || ((sChl[wid][ci + 1] & 255) != q);
        if (lastOfNode) {
            float axs = (ax[0] + ax[1]) + (ax[2] + ax[3]);
            float ays = (ay[0] + ay[1]) + (ay[2] + ay[3]);
            float inv = 1.0f / (float)(deg > 0 ? deg : 1);
            uint32_t o = (uint32_t)f2bf(axs * inv) | ((uint32_t)f2bf(ays * inv) << 16);
            ((uint32_t*)(sIdx + q * 64))[lane] = o;    // agg row overwrites dead idx row
            #pragma unroll
            for (int j = 0; j < 4; ++j) { ax[j] = 0.f; ay[j] = 0.f; }
        }
    };

    if (nch > 0) {
        issue(0, va);
        int i = 0;
        while (true) {
            bool hasB = (i + 1) < nch;
            if (hasB) issue(i + 1, vb);            // overlap: loads(i+1) || accumulate(i)
            consume(i, va, !hasB);
            if (!hasB) break;
            bool hasA = (i + 2) < nch;
            if (hasA) issue(i + 2, va);
            consume(i + 1, vb, !hasA);
            if (!hasA) break;
            i += 2;
        }
    }

    // ---- phase 2: MFMA over the wave's own strip. A = [LDS agg | global h] ----
    int row  = lane & 15;
    int quad = lane >> 4;
    short8 a[8];
    const ushort* srow = (const ushort*)sIdx + row * 128 + quad * 8;  // agg tile rows
    #pragma unroll
    for (int ks = 0; ks < 4; ++ks) a[ks] = *(const short8*)(srow + ks * 32);  // LDS b128
    const ushort* hrow = h_in + (size_t)(r0 + row) * DIM + quad * 8;
    #pragma unroll
    for (int ks = 0; ks < 4; ++ks) a[4 + ks] = *(const short8*)(hrow + ks * 32);

    #pragma unroll 1
    for (int ct = 0; ct < 8; ++ct) {               // full 128 output cols per wave
        int col = ct * 16 + row;
        const ushort* wrow = Wt + (size_t)col * K2 + quad * 8;
        floatx4 acc = {0.f, 0.f, 0.f, 0.f};
        #pragma unroll
        for (int ks = 0; ks < 8; ++ks) {
            short8 b = *(const short8*)(wrow + ks * 32);
            acc = __builtin_amdgcn_mfma_f32_16x16x32_bf16(a[ks], b, acc, 0, 0, 0);
        }
        float bv = bias[col];
        float v[4];
        #pragma unroll
        for (int r = 0; r < 4; ++r) {
            float u = acc[r] + bv;                 // C/D: col=lane&15, row=quad*4+reg
            v[r] = u > 0.f ? u : 0.f;
        }
        if (MODE < 2) {
            #pragma unroll
            for (int r = 0; r < 4; ++r)
                __builtin_nontemporal_store(f2bf(v[r]),
                    &out_bf[(size_t)(r0 + quad * 4 + r) * DIM + col]);
        } else {
            // in-register segmented mean/max readout (usually 1 segment per strip)
            int s0 = 0;
            while (s0 < 16) {
                int g  = sGb[wid][s0];
                int s1 = s0 + 1;
                while (s1 < 16 && sGb[wid][s1] == g) ++s1;
                float sm = 0.f, mx = 0.f;
                #pragma unroll
                for (int r = 0; r < 4; ++r) {
                    int rr = quad * 4 + r;
                    bool in = (rr >= s0) && (rr < s1);
                    sm += in ? v[r] : 0.f;
                    mx = fmaxf(mx, in ? v[r] : 0.f);
                }
                sm += __shfl_xor(sm, 16, 64);
                sm += __shfl_xor(sm, 32, 64);
                mx = fmaxf(mx, __shfl_xor(mx, 16, 64));
                mx = fmaxf(mx, __shfl_xor(mx, 32, 64));
                if (quad == 0) {                   // lanes 0..15 hold per-col totals
                    atomicAdd(&gout[g * 2 * DIM + col], sm);
                    atomicMax((int*)&gout[g * 2 * DIM + DIM + col], __float_as_int(mx));
                }
                s0 = s1;
            }
        }
    }
}

__global__ __launch_bounds__(256) void k_finalize(float* __restrict__ out,
                                                  const int* __restrict__ gstart,
                                                  const int* __restrict__ gend) {
    int i = blockIdx.x * 256 + threadIdx.x;
    if (i < N_GRAPHS * DIM) {
        int g = i / DIM, d = i % DIM;
        int c = gend[g] - gstart[g];
        out[g * 2 * DIM + d] /= (float)(c > 0 ? c : 1);
    }
}

extern "C" void kernel_launch(void* const* d_in, const int* in_sizes, int n_in,
                              void* d_out, int out_size, void* d_ws, size_t ws_size,
                              hipStream_t stream) {
    const float* x     = (const float*)d_in[0];
    const int*   ei    = (const int*)d_in[1];
    const int*   src   = ei;
    const int*   dst   = ei + N_EDGES;
    const int*   batch = (const int*)d_in[2];
    const float* Wl[3] = {(const float*)d_in[3], (const float*)d_in[6], (const float*)d_in[9]};
    const float* bl[3] = {(const float*)d_in[4], (const float*)d_in[7], (const float*)d_in[10]};
    const float* Wr[3] = {(const float*)d_in[5], (const float*)d_in[8], (const float*)d_in[11]};
    float* out = (float*)d_out;

    char* base = (char*)d_ws;
    size_t o = 0;
    auto alloc = [&](size_t b) -> char* {
        char* p = base + o;
        o = (o + b + 255) & ~(size_t)255;
        return p;
    };
    int*     gstart = (int*)alloc((size_t)N_GRAPHS * 4);
    int*     gend   = (int*)alloc((size_t)N_GRAPHS * 4);
    int*     cnt    = (int*)alloc((size_t)N_NODES * 4);
    int*     padded = (int*)alloc((size_t)N_NODES * PAD_CAP * 4);    // 12.8 MB
    ushort*  xb     = (ushort*)alloc((size_t)N_NODES * DIM * 2);
    ushort*  ha     = (ushort*)alloc((size_t)N_NODES * DIM * 2);
    ushort*  hb     = (ushort*)alloc((size_t)N_NODES * DIM * 2);
    ushort*  Wt     = (ushort*)alloc((size_t)3 * DIM * K2 * 2);
    (void)ws_size; (void)n_in; (void)in_sizes; (void)out_size;

    const int LGRID = (N_STRIPS + 3) / 4;          // 782 blocks x 4 independent waves

    // 6 dispatches total
    k_misc<<<MB_OUT, 256, 0, stream>>>(x, xb, Wl[0], Wr[0], Wl[1], Wr[1], Wl[2], Wr[2],
                                       Wt, batch, gstart, gend, cnt, out);
    k_build_direct<<<(N_EDGES + 255) / 256, 256, 0, stream>>>(src, dst, cnt, padded);

    k_layer<0><<<LGRID, 256, 0, stream>>>(xb, padded, cnt, Wt,                bl[0], ha, batch, out);
    k_layer<1><<<LGRID, 256, 0, stream>>>(ha, padded, cnt, Wt + DIM * K2,     bl[1], hb, batch, out);
    k_layer<2><<<LGRID, 256, 0, stream>>>(hb, padded, cnt, Wt + 2 * DIM * K2, bl[2], nullptr, batch, out);

    k_finalize<<<(N_GRAPHS * DIM + 255) / 256, 256, 0, stream>>>(out, gstart, gend);
}

// Round 7
// 354.593 us; speedup vs baseline: 1.0370x; 1.0370x over previous
//
#include <hip/hip_runtime.h>
#include <hip/hip_bf16.h>
#include <stdint.h>

#define N_NODES  50000
#define N_GRAPHS 256
#define DIM      128
#define N_EDGES  800000
#define K2       256            // fused K = [agg | h]
#define N_STRIPS (N_NODES / 16) // 3125, exact
#define PAD_CAP  64             // max degree slack (mean 16; fixed edge list, no overflow)

typedef __attribute__((ext_vector_type(8))) short  short8;
typedef __attribute__((ext_vector_type(4))) float  floatx4;
typedef __attribute__((ext_vector_type(4))) int    intx4;

__device__ __forceinline__ ushort f2bf(float f) {
    union { float f; uint32_t u; } c; c.f = f;
    uint32_t u = c.u;
    return (ushort)((u + 0x7fffu + ((u >> 16) & 1u)) >> 16);  // RNE
}

// ---------- fused prep: convert_x | prep_w | gbounds | cnt-zero | out-zero ----------
#define MB_CONV 6250
#define MB_PREPW (MB_CONV + 384)
#define MB_GB   (MB_PREPW + 196)
#define MB_CNT  (MB_GB + 196)
#define MB_OUT  (MB_CNT + 256)
__global__ __launch_bounds__(256) void k_misc(const float* __restrict__ x, ushort* __restrict__ xb,
                                              const float* __restrict__ Wl0, const float* __restrict__ Wr0,
                                              const float* __restrict__ Wl1, const float* __restrict__ Wr1,
                                              const float* __restrict__ Wl2, const float* __restrict__ Wr2,
                                              ushort* __restrict__ Wt,
                                              const int* __restrict__ batch,
                                              int* __restrict__ gstart, int* __restrict__ gend,
                                              int* __restrict__ cnt, float* __restrict__ out) {
    int b = blockIdx.x, t = threadIdx.x;
    if (b < MB_CONV) {                       // fp32 x -> bf16 (float4 granularity)
        int i = b * 256 + t;                 // i < 1.6M exactly
        float4 v = ((const float4*)x)[i];
        uint32_t lo = (uint32_t)f2bf(v.x) | ((uint32_t)f2bf(v.y) << 16);
        uint32_t hi = (uint32_t)f2bf(v.z) | ((uint32_t)f2bf(v.w) << 16);
        ((uint2*)xb)[i] = make_uint2(lo, hi);
    } else if (b < MB_PREPW) {               // Wt[l][n][k] = bf16(k<128 ? Wl[k][n] : Wr[k-128][n])
        int i = (b - MB_CONV) * 256 + t;     // i < 98304 exactly
        int layer = i / (DIM * K2);
        int j = i % (DIM * K2);
        int n = j / K2, k = j % K2;
        const float* Wl = (layer == 0) ? Wl0 : (layer == 1) ? Wl1 : Wl2;
        const float* Wr = (layer == 0) ? Wr0 : (layer == 1) ? Wr1 : Wr2;
        float v = (k < DIM) ? Wl[k * DIM + n] : Wr[(k - DIM) * DIM + n];
        Wt[i] = f2bf(v);
    } else if (b < MB_GB) {                  // per-graph node ranges from sorted batch
        int i = (b - MB_PREPW) * 256 + t;
        if (i < N_NODES) {
            int g = batch[i];
            if (i == 0) gstart[g] = 0;
            int gn = (i + 1 < N_NODES) ? batch[i + 1] : -1;
            if (gn != g) {
                gend[g] = i + 1;
                if (gn >= 0) gstart[gn] = i + 1;
            }
        }
    } else if (b < MB_CNT) {                 // zero degree counters (pre-build)
        int i = (b - MB_GB) * 256 + t;
        if (i < N_NODES) cnt[i] = 0;
    } else {                                 // zero output (pre-readout atomics)
        int i = (b - MB_CNT) * 256 + t;
        if (i < N_GRAPHS * 2 * DIM) out[i] = 0.f;
    }
}

// ---------- direct adjacency build: one kernel, global atomics ----------
// Insertion order is nondeterministic; k_layer<0> sorts each list before any use, so
// every consumer sees a canonical (ascending) list. Scatter write is nontemporal to
// avoid read-for-ownership traffic on the random 4B writes.
__global__ __launch_bounds__(256) void k_build_direct(const int* __restrict__ src,
                                                      const int* __restrict__ dst,
                                                      int* __restrict__ cnt,
                                                      int* __restrict__ padded) {
    int i = blockIdx.x * 256 + threadIdx.x;
    if (i < N_EDGES) {
        int d = dst[i], s = src[i];
        int p = atomicAdd(&cnt[d], 1);
        if (p < PAD_CAP) __builtin_nontemporal_store(s, &padded[(size_t)d * PAD_CAP + p]);
    }
}

// ---------- fused SAGE layer (R5 block-strip structure + TRIPLE-buffered gather) ----------
// MODE 0: in-wave bitonic sort of each list + canonical writeback for layers 1-2.
// MODE 1: plain middle layer (bf16 out).
// MODE 2: last layer; 8 KB LDS f32 tile + in-block per-graph mean/max readout.
// Phase 1 gather: 3 chunks (48 row-loads) in flight per wave; consume(i) waits at
// vmcnt(32) — two full chunks of slack absorb in-order-retire stragglers.
template <int MODE>
__global__ __launch_bounds__(256) void k_layer(const ushort* __restrict__ h_in,
                                               int* __restrict__ padded,
                                               const int* __restrict__ cnt,
                                               const ushort* __restrict__ Wt,
                                               const float* __restrict__ bias,
                                               ushort* __restrict__ out_bf,
                                               const int* __restrict__ batch,
                                               float* __restrict__ gout) {
    __shared__ ushort sAgg[16 * DIM];              // 4 KB
    __shared__ int    sIdx[16 * PAD_CAP];          // 4 KB neighbor lists
    __shared__ int    sCnt[16];
    __shared__ int    sChl[4][17];                 // per-wave chunk list: q | (e0<<8)
    __shared__ int    sNch[4];
    __shared__ int    sGb[(MODE == 2) ? 16 : 1];   // per-row graph ids (MODE 2)
    __shared__ float  hTile[(MODE == 2) ? 16 * DIM : 1];  // 8 KB f32 out tile (MODE 2)

    int t    = threadIdx.x;
    int wid  = t >> 6;
    int lane = t & 63;
    int r0   = blockIdx.x * 16;
    const uint32_t* hw = (const uint32_t*)h_in;    // 64 dwords per row

    // ---- stage neighbor lists + degrees (coalesced, nontemporal) ----
    ((intx4*)sIdx)[t] = __builtin_nontemporal_load(
        ((const intx4*)(padded + (size_t)r0 * PAD_CAP)) + t);
    if (t < 16) sCnt[t] = cnt[r0 + t];
    if (MODE == 2 && t >= 16 && t < 32) sGb[t - 16] = batch[r0 + t - 16];
    __syncthreads();

    // ---- MODE 0: canonicalize lists in-wave (4 sequential 64-lane bitonics) ----
    if (MODE == 0) {
        #pragma unroll
        for (int q = 0; q < 4; ++q) {
            int nl  = wid * 4 + q;
            int m   = min(sCnt[nl], PAD_CAP);
            int* lst = sIdx + nl * PAD_CAP;
            int v = (lane < m) ? lst[lane] : 0x7fffffff;   // pads sort to the end
            #pragma unroll
            for (int k = 2; k <= 64; k <<= 1) {
                #pragma unroll
                for (int j = k >> 1; j > 0; j >>= 1) {
                    int other  = __shfl_xor(v, j, 64);
                    bool down  = (lane & k) != 0;
                    bool lower = (lane & j) == 0;
                    v = (lower ^ down) ? min(v, other) : max(v, other);
                }
            }
            if (lane < m) {
                lst[lane] = v;                             // wave-local LDS, no barrier
                __builtin_nontemporal_store(v,             // canonical list for layers 1-2
                    &padded[(size_t)(r0 + nl) * PAD_CAP + lane]);
            }
        }
    }

    // ---- per-wave flattened chunk list (wave-uniform; lane 0 writes) ----
    if (lane == 0) {
        int n = 0;
        #pragma unroll
        for (int q = 0; q < 4; ++q) {
            int m = min(sCnt[wid * 4 + q], PAD_CAP);
            for (int e0 = 0; e0 < m; e0 += 16)
                sChl[wid][n++] = q | (e0 << 8);
        }
        sNch[wid] = n;
    }
    // zero agg rows for isolated nodes (no chunks emitted for them)
    #pragma unroll
    for (int q = 0; q < 4; ++q) {
        int node = wid * 4 + q;
        if (sCnt[node] == 0) ((uint32_t*)(sAgg + node * DIM))[lane] = 0u;
    }
    int nch = sNch[wid];

    float ax[4] = {0.f, 0.f, 0.f, 0.f};
    float ay[4] = {0.f, 0.f, 0.f, 0.f};
    uint32_t va[16], vb[16], vc[16];               // TRIPLE-buffered gather rows

    auto issue = [&](int ci, uint32_t (&v)[16]) {
        int ch   = sChl[wid][ci];
        int q    = ch & 255, e0 = ch >> 8;
        int node = wid * 4 + q;
        int m    = min(sCnt[node], PAD_CAP);
        const int* lst = sIdx + node * PAD_CAP;
        #pragma unroll
        for (int k = 0; k < 16; ++k) {
            int ek = e0 + k;
            int id = lst[ek < m ? ek : m - 1];     // LDS broadcast; m>=1 here
            v[k] = hw[(size_t)id * 64 + lane];     // 16 row loads in flight
        }
    };
    auto consume = [&](int ci, uint32_t (&v)[16], bool isLast) {
        int ch   = sChl[wid][ci];
        int q    = ch & 255, e0 = ch >> 8;
        int node = wid * 4 + q;
        int deg  = sCnt[node];
        int m    = min(deg, PAD_CAP);
        #pragma unroll
        for (int k = 0; k < 16; ++k) {
            uint32_t w = (e0 + k < m) ? v[k] : 0u; // predicated tail (bf16 +0.0)
            ax[k & 3] += __uint_as_float(w << 16);
            ay[k & 3] += __uint_as_float(w & 0xffff0000u);
        }
        bool lastOfNode = isLast || ((sChl[wid][ci + 1] & 255) != q);
        if (lastOfNode) {
            float axs = (ax[0] + ax[1]) + (ax[2] + ax[3]);
            float ays = (ay[0] + ay[1]) + (ay[2] + ay[3]);
            float inv = 1.0f / (float)(deg > 0 ? deg : 1);
            uint32_t o = (uint32_t)f2bf(axs * inv) | ((uint32_t)f2bf(ays * inv) << 16);
            ((uint32_t*)(sAgg + node * DIM))[lane] = o;
            #pragma unroll
            for (int j = 0; j < 4; ++j) { ax[j] = 0.f; ay[j] = 0.f; }
        }
    };

    if (nch > 0) {
        issue(0, va);
        if (nch > 1) issue(1, vb);                 // 2 chunks in flight at first consume
        int i = 0;
        for (;;) {
            if (i + 2 < nch) issue(i + 2, vc);     // 3rd chunk joins the queue
            consume(i, va, i + 1 >= nch);
            if (++i >= nch) break;
            if (i + 2 < nch) issue(i + 2, va);
            consume(i, vb, i + 1 >= nch);
            if (++i >= nch) break;
            if (i + 2 < nch) issue(i + 2, vb);
            consume(i, vc, i + 1 >= nch);
            if (++i >= nch) break;
        }
    }
    __syncthreads();

    // ---- phase 2: MFMA. A-frags: lane holds A[m=lane&15][k=quad*8+j] ----
    int row  = lane & 15;
    int quad = lane >> 4;
    short8 a[8];
    const ushort* srow = sAgg + row * DIM + quad * 8;
    #pragma unroll
    for (int ks = 0; ks < 4; ++ks) a[ks] = *(const short8*)(srow + ks * 32);  // LDS b128
    const ushort* hrow = h_in + (size_t)(r0 + row) * DIM + quad * 8;
    #pragma unroll
    for (int ks = 0; ks < 4; ++ks) a[4 + ks] = *(const short8*)(hrow + ks * 32);

    #pragma unroll
    for (int c = 0; c < 2; ++c) {
        int ct  = wid * 2 + c;                     // 4 waves x 2 = 8 col-tiles
        int col = ct * 16 + row;
        const ushort* wrow = Wt + (size_t)col * K2 + quad * 8;
        floatx4 acc = {0.f, 0.f, 0.f, 0.f};
        #pragma unroll
        for (int ks = 0; ks < 8; ++ks) {
            short8 b = *(const short8*)(wrow + ks * 32);
            acc = __builtin_amdgcn_mfma_f32_16x16x32_bf16(a[ks], b, acc, 0, 0, 0);
        }
        float bv = bias[col];
        #pragma unroll
        for (int r = 0; r < 4; ++r) {
            int m = r0 + quad * 4 + r;             // C/D: col=lane&15, row=quad*4+reg
            float v = acc[r] + bv;
            v = v > 0.f ? v : 0.f;
            if (MODE < 2) __builtin_nontemporal_store(f2bf(v), &out_bf[(size_t)m * DIM + col]);
            else          hTile[(quad * 4 + r) * DIM + col] = v;
        }
    }

    // ---- MODE 2: in-block mean/max readout (batch sorted -> run-length flush) ----
    if (MODE == 2) {
        __syncthreads();
        int d     = t & 127;
        bool doMax = t >= 128;                     // threads 0-127: sum; 128-255: max
        float s = 0.f, mx = 0.f;
        int cur = sGb[0];
        #pragma unroll
        for (int m = 0; m < 16; ++m) {
            int g = sGb[m];
            if (g != cur) {
                if (doMax) atomicMax((int*)&gout[cur * 2 * DIM + DIM + d], __float_as_int(mx));
                else       atomicAdd(&gout[cur * 2 * DIM + d], s);
                cur = g; s = 0.f; mx = 0.f;
            }
            float v = hTile[m * DIM + d];
            s += v; mx = fmaxf(mx, v);
        }
        if (doMax) atomicMax((int*)&gout[cur * 2 * DIM + DIM + d], __float_as_int(mx));
        else       atomicAdd(&gout[cur * 2 * DIM + d], s);
    }
}

__global__ __launch_bounds__(256) void k_finalize(float* __restrict__ out,
                                                  const int* __restrict__ gstart,
                                                  const int* __restrict__ gend) {
    int i = blockIdx.x * 256 + threadIdx.x;
    if (i < N_GRAPHS * DIM) {
        int g = i / DIM, d = i % DIM;
        int c = gend[g] - gstart[g];
        out[g * 2 * DIM + d] /= (float)(c > 0 ? c : 1);
    }
}

extern "C" void kernel_launch(void* const* d_in, const int* in_sizes, int n_in,
                              void* d_out, int out_size, void* d_ws, size_t ws_size,
                              hipStream_t stream) {
    const float* x     = (const float*)d_in[0];
    const int*   ei    = (const int*)d_in[1];
    const int*   src   = ei;
    const int*   dst   = ei + N_EDGES;
    const int*   batch = (const int*)d_in[2];
    const float* Wl[3] = {(const float*)d_in[3], (const float*)d_in[6], (const float*)d_in[9]};
    const float* bl[3] = {(const float*)d_in[4], (const float*)d_in[7], (const float*)d_in[10]};
    const float* Wr[3] = {(const float*)d_in[5], (const float*)d_in[8], (const float*)d_in[11]};
    float* out = (float*)d_out;

    char* base = (char*)d_ws;
    size_t o = 0;
    auto alloc = [&](size_t b) -> char* {
        char* p = base + o;
        o = (o + b + 255) & ~(size_t)255;
        return p;
    };
    int*     gstart = (int*)alloc((size_t)N_GRAPHS * 4);
    int*     gend   = (int*)alloc((size_t)N_GRAPHS * 4);
    int*     cnt    = (int*)alloc((size_t)N_NODES * 4);
    int*     padded = (int*)alloc((size_t)N_NODES * PAD_CAP * 4);    // 12.8 MB
    ushort*  xb     = (ushort*)alloc((size_t)N_NODES * DIM * 2);
    ushort*  ha     = (ushort*)alloc((size_t)N_NODES * DIM * 2);
    ushort*  hb     = (ushort*)alloc((size_t)N_NODES * DIM * 2);
    ushort*  Wt     = (ushort*)alloc((size_t)3 * DIM * K2 * 2);
    (void)ws_size; (void)n_in; (void)in_sizes; (void)out_size;

    // 6 dispatches total
    k_misc<<<MB_OUT, 256, 0, stream>>>(x, xb, Wl[0], Wr[0], Wl[1], Wr[1], Wl[2], Wr[2],
                                       Wt, batch, gstart, gend, cnt, out);
    k_build_direct<<<(N_EDGES + 255) / 256, 256, 0, stream>>>(src, dst, cnt, padded);

    k_layer<0><<<N_STRIPS, 256, 0, stream>>>(xb, padded, cnt, Wt,                bl[0], ha, batch, out);
    k_layer<1><<<N_STRIPS, 256, 0, stream>>>(ha, padded, cnt, Wt + DIM * K2,     bl[1], hb, batch, out);
    k_layer<2><<<N_STRIPS, 256, 0, stream>>>(hb, padded, cnt, Wt + 2 * DIM * K2, bl[2], nullptr, batch, out);

    k_finalize<<<(N_GRAPHS * DIM + 255) / 256, 256, 0, stream>>>(out, gstart, gend);
}